// Round 3
// baseline (387.908 us; speedup 1.0000x reference)
//
#include <hip/hip_runtime.h>
#include <hip/hip_bf16.h>
#include <math.h>

typedef __hip_bfloat16 bf16;
typedef __bf16 bf16x8 __attribute__((ext_vector_type(8)));
typedef float  f32x4  __attribute__((ext_vector_type(4)));

#define DEVI __device__ __forceinline__

static constexpr int Bb     = 2;
static constexpr int Ss     = 2048;
static constexpr int DMODEL = 1024;
static constexpr int NTOK   = Bb * Ss;   // 4096

DEVI float bf2f(bf16 v) { return __bfloat162float(v); }
DEVI bf16  f2bf(float v) { return __float2bfloat16(v); }

// ---------------------------------------------------------------- fp32 -> bf16 convert
__global__ __launch_bounds__(256) void convert_kernel(
    const float* __restrict__ in, bf16* __restrict__ out, int n4) {
  const int t = blockIdx.x * blockDim.x + threadIdx.x;
  if (t >= n4) return;
  const float4 v = ((const float4*)in)[t];
  bf16 o[4] = { f2bf(v.x), f2bf(v.y), f2bf(v.z), f2bf(v.w) };
  *(ushort4*)&out[(size_t)t * 4] = *(const ushort4*)o;
}

// ---------------------------------------------------------------- transpose (+convert)
// out[c][r] = bf16(in[r][c]), R,C multiples of 64
template <typename TIN>
__global__ __launch_bounds__(256) void transpose_kernel(
    const TIN* __restrict__ in, bf16* __restrict__ out, int R, int C) {
  __shared__ bf16 t[64][65];
  const int r0 = blockIdx.y * 64, c0 = blockIdx.x * 64;
  const int tc = threadIdx.x & 63, tr = threadIdx.x >> 6;
#pragma unroll
  for (int p = 0; p < 16; ++p) {
    int r = tr + p * 4;
    t[r][tc] = f2bf((float)in[(size_t)(r0 + r) * C + c0 + tc]);
  }
  __syncthreads();
#pragma unroll
  for (int p = 0; p < 16; ++p) {
    int r = tr + p * 4;   // row of out tile = col of in tile
    out[(size_t)(c0 + r) * R + r0 + tc] = t[tc][r];
  }
}

// ---------------------------------------------------------------- GEMM
// C(M,N) = A(M,K) @ WT(N,K)^T + bias, 128x128 tile, BK=32, 4 waves, reg-staged
template <int OUT_F32>
__global__ __launch_bounds__(256) void gemm_kernel(
    const bf16* __restrict__ A, const bf16* __restrict__ WT,
    const float* __restrict__ bias, void* __restrict__ Cout,
    int M, int N, int K) {
  __shared__ bf16 ldsA[128 * 32];
  __shared__ bf16 ldsB[128 * 32];
  const int tid = threadIdx.x;
  const int lane = tid & 63;
  const int w = tid >> 6;          // wave 0..3
  const int wr = w >> 1, wc = w & 1;
  const int tileM = blockIdx.y * 128;
  const int tileN = blockIdx.x * 128;
  const int l15 = lane & 15, lg = lane >> 4;
  const int lrow = lane >> 2;          // 0..15
  const int lcol = (lane & 3) * 8;     // 0,8,16,24

  f32x4 acc[4][4] = {};

  for (int k0 = 0; k0 < K; k0 += 32) {
    bf16x8 va0 = *(const bf16x8*)(A  + (size_t)(tileM + w * 32 +      lrow) * K + k0 + lcol);
    bf16x8 va1 = *(const bf16x8*)(A  + (size_t)(tileM + w * 32 + 16 + lrow) * K + k0 + lcol);
    bf16x8 vb0 = *(const bf16x8*)(WT + (size_t)(tileN + w * 32 +      lrow) * K + k0 + lcol);
    bf16x8 vb1 = *(const bf16x8*)(WT + (size_t)(tileN + w * 32 + 16 + lrow) * K + k0 + lcol);
    *(bf16x8*)&ldsA[(w * 32 +      lrow) * 32 + lcol] = va0;
    *(bf16x8*)&ldsA[(w * 32 + 16 + lrow) * 32 + lcol] = va1;
    *(bf16x8*)&ldsB[(w * 32 +      lrow) * 32 + lcol] = vb0;
    *(bf16x8*)&ldsB[(w * 32 + 16 + lrow) * 32 + lcol] = vb1;
    __syncthreads();

    bf16x8 af[4], bfr[4];
#pragma unroll
    for (int i = 0; i < 4; ++i) {
      af[i]  = *(const bf16x8*)&ldsA[(wr * 64 + i * 16 + l15) * 32 + lg * 8];
      bfr[i] = *(const bf16x8*)&ldsB[(wc * 64 + i * 16 + l15) * 32 + lg * 8];
    }
#pragma unroll
    for (int i = 0; i < 4; ++i)
#pragma unroll
      for (int j = 0; j < 4; ++j)
        acc[i][j] = __builtin_amdgcn_mfma_f32_16x16x32_bf16(af[i], bfr[j], acc[i][j], 0, 0, 0);
    __syncthreads();
  }

  const int mbase = tileM + wr * 64;
  const int nbase = tileN + wc * 64;
#pragma unroll
  for (int j = 0; j < 4; ++j) {
    int col = nbase + j * 16 + l15;
    float bv = bias[col];
#pragma unroll
    for (int i = 0; i < 4; ++i)
#pragma unroll
      for (int r = 0; r < 4; ++r) {
        int row = mbase + i * 16 + lg * 4 + r;
        float v = acc[i][j][r] + bv;
        if (OUT_F32) ((float*)Cout)[(size_t)row * N + col] = v;
        else         ((bf16*)Cout)[(size_t)row * N + col]  = f2bf(v);
      }
  }
}

// ---------------------------------------------------------------- combine + rope
// out = bf16(Gc + rope(Gr)); one thread per (token, pair); trig on the fly
__global__ __launch_bounds__(256) void combine_rope_kernel(
    const bf16* __restrict__ Gc, const bf16* __restrict__ Gr,
    bf16* __restrict__ out) {
  const int t = blockIdx.x * blockDim.x + threadIdx.x;   // NTOK*512 threads
  const int p = t & 511;
  const int row = t >> 9;
  const int s = row & (Ss - 1);
  // theta = 10000^(-2p)/512 ; log2(10000) = 13.287712379549449
  float theta = exp2f(-2.0f * (float)p * 13.2877123795494f) * (1.0f / 512.0f);
  float r = (float)s * theta;
  float c = cosf(r), sn = sinf(r);
  const size_t base = (size_t)row * DMODEL + 2 * p;
  const float g0 = bf2f(Gr[base]), g1 = bf2f(Gr[base + 1]);
  out[base]     = f2bf(bf2f(Gc[base])     + g0 * c - g1 * sn);
  out[base + 1] = f2bf(bf2f(Gc[base + 1]) + g1 * c + g0 * sn);
}

// ---------------------------------------------------------------- attention
// grid (16 q-tiles, 32 bh); 4 waves x 32 q-rows; KV tile = 64
__global__ __launch_bounds__(256) void attn_kernel(
    const bf16* __restrict__ Qn, const bf16* __restrict__ Kn,
    const bf16* __restrict__ VT, bf16* __restrict__ AO) {
  const int qt = blockIdx.x;
  const int bh = blockIdx.y;
  const int b = bh >> 4, h = bh & 15;
  const int tid = threadIdx.x, lane = tid & 63, w = tid >> 6;
  const int q0 = qt * 128 + w * 32;
  const int l15 = lane & 15, lg = lane >> 4;
  const float INV_SCALE = 0.031008684f;   // 1/sqrt(16+512+512)

  __shared__ bf16 P[4][32][72];           // per-wave, padded rows

  bf16x8 aq[2][2];
#pragma unroll
  for (int i = 0; i < 2; ++i)
#pragma unroll
    for (int kg = 0; kg < 2; ++kg)
      aq[i][kg] = *(const bf16x8*)&Qn[(size_t)(b * Ss + q0 + i * 16 + l15) * DMODEL +
                                      h * 64 + kg * 32 + lg * 8];

  float mrow[2][4], lrow[2][4];
  f32x4 accO[2][4] = {};
#pragma unroll
  for (int i = 0; i < 2; ++i)
#pragma unroll
    for (int r = 0; r < 4; ++r) { mrow[i][r] = -3.0e38f; lrow[i][r] = 0.f; }

  for (int kv0 = 0; kv0 < Ss; kv0 += 64) {
    // ---- S = Q K^T
    f32x4 sa[2][4] = {};
#pragma unroll
    for (int kg = 0; kg < 2; ++kg) {
      bf16x8 bk[4];
#pragma unroll
      for (int j = 0; j < 4; ++j)
        bk[j] = *(const bf16x8*)&Kn[(size_t)(b * Ss + kv0 + j * 16 + l15) * DMODEL +
                                    h * 64 + kg * 32 + lg * 8];
#pragma unroll
      for (int i = 0; i < 2; ++i)
#pragma unroll
        for (int j = 0; j < 4; ++j)
          sa[i][j] = __builtin_amdgcn_mfma_f32_16x16x32_bf16(aq[i][kg], bk[j], sa[i][j], 0, 0, 0);
    }
    // ---- online softmax (row lives in a 16-lane group)
#pragma unroll
    for (int i = 0; i < 2; ++i)
#pragma unroll
      for (int r = 0; r < 4; ++r) {
        float v0 = sa[i][0][r] * INV_SCALE, v1 = sa[i][1][r] * INV_SCALE;
        float v2 = sa[i][2][r] * INV_SCALE, v3 = sa[i][3][r] * INV_SCALE;
        float tmax = fmaxf(fmaxf(v0, v1), fmaxf(v2, v3));
#pragma unroll
        for (int d = 1; d < 16; d <<= 1) tmax = fmaxf(tmax, __shfl_xor(tmax, d, 64));
        float mnew = fmaxf(mrow[i][r], tmax);
        float corr = __expf(mrow[i][r] - mnew);
        float p0 = __expf(v0 - mnew), p1 = __expf(v1 - mnew);
        float p2 = __expf(v2 - mnew), p3 = __expf(v3 - mnew);
        float ts = p0 + p1 + p2 + p3;
#pragma unroll
        for (int d = 1; d < 16; d <<= 1) ts += __shfl_xor(ts, d, 64);
        mrow[i][r] = mnew;
        lrow[i][r] = lrow[i][r] * corr + ts;
#pragma unroll
        for (int dj = 0; dj < 4; ++dj) accO[i][dj][r] *= corr;
        int q = i * 16 + lg * 4 + r;
        P[w][q][0 * 16 + l15] = f2bf(p0);
        P[w][q][1 * 16 + l15] = f2bf(p1);
        P[w][q][2 * 16 + l15] = f2bf(p2);
        P[w][q][3 * 16 + l15] = f2bf(p3);
      }
    __syncthreads();
    // ---- O += P V
#pragma unroll
    for (int kp = 0; kp < 2; ++kp) {
      bf16x8 pv[2];
#pragma unroll
      for (int i = 0; i < 2; ++i)
        pv[i] = *(const bf16x8*)&P[w][i * 16 + l15][kp * 32 + lg * 8];
#pragma unroll
      for (int dj = 0; dj < 4; ++dj) {
        bf16x8 bv = *(const bf16x8*)&VT[(size_t)(h * 64 + dj * 16 + l15) * NTOK +
                                        b * Ss + kv0 + kp * 32 + lg * 8];
#pragma unroll
        for (int i = 0; i < 2; ++i)
          accO[i][dj] = __builtin_amdgcn_mfma_f32_16x16x32_bf16(pv[i], bv, accO[i][dj], 0, 0, 0);
      }
    }
  }

#pragma unroll
  for (int i = 0; i < 2; ++i)
#pragma unroll
    for (int dj = 0; dj < 4; ++dj)
#pragma unroll
      for (int r = 0; r < 4; ++r) {
        int q = q0 + i * 16 + lg * 4 + r;
        float o = accO[i][dj][r] / lrow[i][r];
        AO[(size_t)(b * Ss + q) * DMODEL + h * 64 + dj * 16 + l15] = f2bf(o);
      }
}

// ---------------------------------------------------------------- launch
extern "C" void kernel_launch(void* const* d_in, const int* in_sizes, int n_in,
                              void* d_out, int out_size, void* d_ws, size_t ws_size,
                              hipStream_t stream) {
  // fp32 inputs (per reference setup_inputs dtypes)
  const float* x      = (const float*)d_in[0];
  const float* Wdq    = (const float*)d_in[1];  const float* Wdq_b  = (const float*)d_in[2];
  const float* Wuq    = (const float*)d_in[3];  const float* Wuq_b  = (const float*)d_in[4];
  const float* Wqr    = (const float*)d_in[5];  const float* Wqr_b  = (const float*)d_in[6];
  const float* Wkr    = (const float*)d_in[7];  const float* Wkr_b  = (const float*)d_in[8];
  const float* Wdkv   = (const float*)d_in[9];  const float* Wdkv_b = (const float*)d_in[10];
  const float* Wuk    = (const float*)d_in[11]; const float* Wuk_b  = (const float*)d_in[12];
  const float* Wuv    = (const float*)d_in[13]; const float* Wuv_b  = (const float*)d_in[14];
  const float* Wo     = (const float*)d_in[15]; const float* Wo_b   = (const float*)d_in[16];

  // ---- workspace slots (~52 MB, explicit lifetimes) ----
  char* ws = (char*)d_ws;
  size_t off = 0;
  bf16* WdqT   = (bf16*)(ws + off); off += (size_t)512  * 1024 * 2;
  bf16* WuqT   = (bf16*)(ws + off); off += (size_t)1024 * 512  * 2;
  bf16* WqrT   = (bf16*)(ws + off); off += (size_t)1024 * 512  * 2;
  bf16* WkrT   = (bf16*)(ws + off); off += (size_t)1024 * 1024 * 2;
  bf16* WdkvT  = (bf16*)(ws + off); off += (size_t)512  * 1024 * 2;
  bf16* WukT   = (bf16*)(ws + off); off += (size_t)1024 * 512  * 2;
  bf16* WuvT   = (bf16*)(ws + off); off += (size_t)1024 * 512  * 2;
  bf16* WoT    = (bf16*)(ws + off); off += (size_t)1024 * 1024 * 2;
  bf16* x_bf   = (bf16*)(ws + off); off += (size_t)NTOK * 1024 * 2;
  bf16* ct_q   = (bf16*)(ws + off); off += (size_t)NTOK * 512 * 2;
  bf16* ct_kv  = (bf16*)(ws + off); off += (size_t)NTOK * 512 * 2;
  bf16* Ga     = (bf16*)(ws + off); off += (size_t)NTOK * 1024 * 2;
  bf16* Gb     = (bf16*)(ws + off); off += (size_t)NTOK * 1024 * 2;
  bf16* VTr    = (bf16*)(ws + off); off += (size_t)NTOK * 1024 * 2;
  // Qn/Kn live inside d_out (16.8 MB fp32 slab = 2 x 8.4 MB bf16), dead before final GEMM
  bf16* Qn     = (bf16*)d_out;
  bf16* Kn     = (bf16*)d_out + (size_t)NTOK * DMODEL;
  bf16* AO     = Ga;   // free after K-combine
  (void)ws_size; (void)in_sizes; (void)n_in; (void)out_size;

  // weight transpose+convert (K-major bf16 for MFMA B-operand)
  transpose_kernel<float><<<dim3(512 / 64, 1024 / 64), 256, 0, stream>>>(Wdq,  WdqT,  1024, 512);
  transpose_kernel<float><<<dim3(1024 / 64, 512 / 64), 256, 0, stream>>>(Wuq,  WuqT,  512, 1024);
  transpose_kernel<float><<<dim3(1024 / 64, 512 / 64), 256, 0, stream>>>(Wqr,  WqrT,  512, 1024);
  transpose_kernel<float><<<dim3(1024 / 64, 1024 / 64), 256, 0, stream>>>(Wkr, WkrT, 1024, 1024);
  transpose_kernel<float><<<dim3(512 / 64, 1024 / 64), 256, 0, stream>>>(Wdkv, WdkvT, 1024, 512);
  transpose_kernel<float><<<dim3(1024 / 64, 512 / 64), 256, 0, stream>>>(Wuk,  WukT,  512, 1024);
  transpose_kernel<float><<<dim3(1024 / 64, 512 / 64), 256, 0, stream>>>(Wuv,  WuvT,  512, 1024);
  transpose_kernel<float><<<dim3(1024 / 64, 1024 / 64), 256, 0, stream>>>(Wo,  WoT,  1024, 1024);
  convert_kernel<<<(NTOK * DMODEL / 4 + 255) / 256, 256, 0, stream>>>(x, x_bf, NTOK * DMODEL / 4);

  // down-projections
  gemm_kernel<0><<<dim3(4, 32), 256, 0, stream>>>(x_bf, WdqT,  Wdq_b,  ct_q,  NTOK, 512, 1024);
  gemm_kernel<0><<<dim3(4, 32), 256, 0, stream>>>(x_bf, WdkvT, Wdkv_b, ct_kv, NTOK, 512, 1024);

  // query = up(ct_q) + rope(qr(ct_q)) -> Qn
  gemm_kernel<0><<<dim3(8, 32), 256, 0, stream>>>(ct_q, WuqT, Wuq_b, Ga, NTOK, 1024, 512);
  gemm_kernel<0><<<dim3(8, 32), 256, 0, stream>>>(ct_q, WqrT, Wqr_b, Gb, NTOK, 1024, 512);
  combine_rope_kernel<<<(NTOK * 512) / 256, 256, 0, stream>>>(Ga, Gb, Qn);

  // value path (Ga reused as V temp, then freed by transpose)
  gemm_kernel<0><<<dim3(8, 32), 256, 0, stream>>>(ct_kv, WuvT, Wuv_b, Ga, NTOK, 1024, 512);
  transpose_kernel<bf16><<<dim3(1024 / 64, NTOK / 64), 256, 0, stream>>>(Ga, VTr, NTOK, 1024);

  // key = up(ct_kv) + rope(kr(x)) -> Kn
  gemm_kernel<0><<<dim3(8, 32), 256, 0, stream>>>(ct_kv, WukT, Wuk_b, Ga, NTOK, 1024, 512);
  gemm_kernel<0><<<dim3(8, 32), 256, 0, stream>>>(x_bf,  WkrT, Wkr_b, Gb, NTOK, 1024, 1024);
  combine_rope_kernel<<<(NTOK * 512) / 256, 256, 0, stream>>>(Ga, Gb, Kn);

  // attention: Qn, Kn, VTr -> AO (aliases Ga)
  attn_kernel<<<dim3(16, 32), 256, 0, stream>>>(Qn, Kn, VTr, AO);

  // output projection (reads AO from ws, writes fp32 d_out)
  gemm_kernel<1><<<dim3(8, 32), 256, 0, stream>>>(AO, WoT, Wo_b, (float*)d_out, NTOK, 1024, 1024);
}